// Round 5
// baseline (83.806 us; speedup 1.0000x reference)
//
#include <hip/hip_runtime.h>
#include <type_traits>

// PatcherUnfold: y[b,l,e] = sum_k patches[b,l,k] * W[e,k] + bias[e]
// Implicit GEMM, M=36864 N=768 K=768, bf16 MFMA 16x16x32, fp32 accum.
// Round 5: 4-phase-per-K-tile interleaved schedule (T3+T4), raw s_barrier +
// counted waitcnt (no full drain in loop), setprio around MFMA clusters (T5),
// B via global_load_lds w=16 w/ pre-swizzled source, A reg-staged fp32->bf16
// (issue phase 0, cvt+write phases 2/3), XCD-chunked swizzle, dbuf LDS.

namespace {

constexpr int PB   = 16;
constexpr int Cch  = 3;
constexpr int Him  = 384;
constexpr int Wim  = 384;
constexpr int GWp  = 24;
constexpr int Lp   = 576;
constexpr int Kd   = 768;
constexpr int Nd   = 768;
constexpr int Md   = 64 * Lp;        // 36864
constexpr int BM   = 256;
constexpr int BN   = 256;
constexpr int BK   = 64;
constexpr int NT   = Kd / BK;        // 12
constexpr int ASZ  = BM * BK * 2;    // 32 KiB
constexpr int BSZ  = BN * BK * 2;    // 32 KiB
constexpr int BUFB = ASZ + BSZ;      // 64 KiB per buffer
constexpr int GN   = Nd / BN;        // 3
constexpr int NBLK = (Md / BM) * GN; // 432 = 8 * 54

typedef __bf16 bf16x4 __attribute__((ext_vector_type(4)));
typedef __bf16 bf16x8 __attribute__((ext_vector_type(8)));
typedef float  f32x4  __attribute__((ext_vector_type(4)));

template <int N> using ic = std::integral_constant<int, N>;

__global__ __launch_bounds__(256)
void convert_w(const float* __restrict__ Wm, __bf16* __restrict__ Wb)
{
    const int i = (blockIdx.x * 256 + threadIdx.x) * 4;
    const f32x4 v = *(const f32x4*)(Wm + i);
    bf16x4 h;
    #pragma unroll
    for (int e = 0; e < 4; ++e) h[e] = (__bf16)v[e];
    *(bf16x4*)(Wb + i) = h;
}

__device__ __forceinline__ void gload_lds16(const void* gsrc, void* lds_dst)
{
    __builtin_amdgcn_global_load_lds(
        (const __attribute__((address_space(1))) unsigned int*)gsrc,
        (__attribute__((address_space(3))) unsigned int*)lds_dst,
        16, 0, 0);
}

__device__ __forceinline__ void bar()   { __builtin_amdgcn_s_barrier(); }
__device__ __forceinline__ void wlgkm() { asm volatile("s_waitcnt lgkmcnt(0)" ::: "memory"); }
__device__ __forceinline__ void wvm0()  { asm volatile("s_waitcnt vmcnt(0)" ::: "memory"); }

__global__ __launch_bounds__(512, 1)
void patch_embed_gemm(const float* __restrict__ x,
                      const __bf16* __restrict__ Wb,
                      const float* __restrict__ bias,
                      float* __restrict__ out)
{
    __shared__ __align__(16) unsigned char lds[2 * BUFB]; // 128 KiB

    // XCD-chunked swizzle (432 % 8 == 0 -> bijective), bm-major.
    const int h  = blockIdx.x;
    const int l  = (h & 7) * (NBLK / 8) + (h >> 3);
    const int bm = l / GN;
    const int bn = l - bm * GN;

    const int tid  = threadIdx.x;
    const int lane = tid & 63;
    const int wv   = tid >> 6;   // 0..7
    const int wr   = wv >> 2;    // 0..1  -> 128-row strip
    const int wc   = wv & 3;     // 0..3  -> 64-col strip
    const int fr   = lane & 15;
    const int kg   = lane >> 4;

    // ---- A staging map: thread covers rows r0 + 32*it (it=0..7), chunk q
    const int q    = tid & 15;
    const int r0   = tid >> 4;   // 0..31
    const int px   = (q & 3) * 4;
    const int pyo  = q >> 2;
    const int ldsw = r0 * 128 + ((q * 8) ^ ((r0 & 7) << 4));

    int arow[8];
    #pragma unroll
    for (int it = 0; it < 8; ++it) {
        const int m  = bm * BM + r0 + it * 32;
        const int b  = m / Lp;
        const int li = m - b * Lp;
        const int gy = li / GWp;
        const int gx = li - gy * GWp;
        arow[it] = b * (Cch * Him * Wim) + (gy * PB) * Wim + gx * PB;
    }

    // ---- B staging map (global_load_lds, linear LDS dest, swizzled source)
    const unsigned char* wbase = (const unsigned char*)(Wb + (size_t)(bn * BN) * Kd);
    int boff[4];
    int bdst[4];
    #pragma unroll
    for (int j = 0; j < 4; ++j) {
        const int off = (j * 512 + tid) * 16;
        const int row = off >> 7;
        const int bb  = off & 127;
        boff[j] = row * (Kd * 2) + (bb ^ ((row & 7) << 4));
        bdst[j] = off;
    }

    f32x4 pa[8];

    auto load_A = [&](int t) {
        const int c   = t >> 2;
        const int pyb = (t & 3) * 4;
        const float* xs = x + c * (Him * Wim) + (pyb + pyo) * Wim + px;
        #pragma unroll
        for (int it = 0; it < 8; ++it)
            pa[it] = *(const f32x4*)(xs + arow[it]);
    };

    auto stage_B = [&](int t, unsigned char* nbuf) {
        unsigned char* dst = nbuf + ASZ;
        const unsigned char* src = wbase + t * 128;
        #pragma unroll
        for (int j = 0; j < 4; ++j)
            gload_lds16(src + boff[j], dst + bdst[j]);
    };

    auto store_A_half = [&](unsigned char* nbuf, int lo) {
        #pragma unroll
        for (int it = 0; it < 4; ++it) {
            bf16x4 ha;
            #pragma unroll
            for (int e = 0; e < 4; ++e) ha[e] = (__bf16)pa[lo + it][e];
            *(bf16x4*)(nbuf + ldsw + (lo + it) * 4096) = ha;
        }
    };

    f32x4 acc[8][4];
    #pragma unroll
    for (int i = 0; i < 8; ++i)
        #pragma unroll
        for (int j = 0; j < 4; ++j)
            acc[i][j] = f32x4{0.f, 0.f, 0.f, 0.f};

    bf16x8 br[4][2], ar[2][2];

    auto ds_br = [&](const unsigned char* ldsB) {
        #pragma unroll
        for (int fj = 0; fj < 4; ++fj)
            #pragma unroll
            for (int kk = 0; kk < 2; ++kk) {
                const int rowB = wc * 64 + fj * 16 + fr;
                br[fj][kk] = *(const bf16x8*)(ldsB + rowB * 128 +
                                ((kk * 64 + kg * 16) ^ ((rowB & 7) << 4)));
            }
    };

    auto ds_ar = [&](int fbase, const unsigned char* ldsA) {
        #pragma unroll
        for (int i = 0; i < 2; ++i)
            #pragma unroll
            for (int kk = 0; kk < 2; ++kk) {
                const int rowA = wr * 128 + (fbase + i) * 16 + fr;
                ar[i][kk] = *(const bf16x8*)(ldsA + rowA * 128 +
                                ((kk * 64 + kg * 16) ^ ((rowA & 7) << 4)));
            }
    };

    auto mfma16 = [&](auto FB) {
        constexpr int F = decltype(FB)::value;
        __builtin_amdgcn_s_setprio(1);
        #pragma unroll
        for (int i = 0; i < 2; ++i)
            #pragma unroll
            for (int fj = 0; fj < 4; ++fj)
                #pragma unroll
                for (int kk = 0; kk < 2; ++kk)
                    acc[F + i][fj] = __builtin_amdgcn_mfma_f32_16x16x32_bf16(
                        ar[i][kk], br[fj][kk], acc[F + i][fj], 0, 0, 0);
        __builtin_amdgcn_s_setprio(0);
    };

    // ---- prologue: stage tile 0 into buf0 ----
    load_A(0);
    stage_B(0, lds);
    store_A_half(lds, 0);
    store_A_half(lds, 4);
    wvm0();            // B(0) DMA landed
    wlgkm();           // own ds_writes done
    bar();             // all waves' tile-0 data visible

    // ---- main loop: 4 phases per K-tile, 2 barriers per phase ----
    for (int t = 0; t < NT; ++t) {
        const unsigned char* ldsA = lds + (t & 1) * BUFB;
        const unsigned char* ldsB = ldsA + ASZ;
        unsigned char* nbuf = lds + ((t + 1) & 1) * BUFB;
        const bool pf = (t + 1) < NT;   // uniform

        // phase 0: br(8) + ar fi{0,1}(4); issue all t+1 prefetch
        ds_br(ldsB);
        ds_ar(0, ldsA);
        if (pf) {
            load_A(t + 1);        // global -> regs, consumed phases 2/3
            stage_B(t + 1, nbuf); // DMA -> LDS, waited at tile end
        }
        bar(); wlgkm();
        mfma16(ic<0>{});
        bar();

        // phase 1
        ds_ar(2, ldsA);
        bar(); wlgkm();
        mfma16(ic<2>{});
        bar();

        // phase 2: + cvt/write first A half of t+1
        ds_ar(4, ldsA);
        if (pf) store_A_half(nbuf, 0);
        bar(); wlgkm();
        mfma16(ic<4>{});
        bar();

        // phase 3: + second A half; tile-boundary waits
        ds_ar(6, ldsA);
        if (pf) store_A_half(nbuf, 4);
        bar(); wlgkm();
        mfma16(ic<6>{});
        wvm0();           // B(t+1) DMA landed (issued 4 phases ago)
        bar();            // boundary: next tile may read nbuf
    }

    // epilogue: C/D layout col = lane&15, row = (lane>>4)*4 + j
    const int orow0 = bm * BM + wr * 128;
    const int ocol0 = bn * BN + wc * 64;
    #pragma unroll
    for (int fj = 0; fj < 4; ++fj) {
        const int col = ocol0 + fj * 16 + fr;
        const float bv = bias[col];
        #pragma unroll
        for (int fi = 0; fi < 8; ++fi) {
            const int row = orow0 + fi * 16 + kg * 4;
            #pragma unroll
            for (int j = 0; j < 4; ++j)
                out[(row + j) * Nd + col] = acc[fi][fj][j] + bv;
        }
    }
}

} // namespace

extern "C" void kernel_launch(void* const* d_in, const int* in_sizes, int n_in,
                              void* d_out, int out_size, void* d_ws, size_t ws_size,
                              hipStream_t stream)
{
    (void)in_sizes; (void)n_in; (void)out_size; (void)ws_size;
    const float* x  = (const float*)d_in[0];
    const float* Wm = (const float*)d_in[1];
    const float* bs = (const float*)d_in[2];
    float* outp = (float*)d_out;
    __bf16* Wb = (__bf16*)d_ws;   // 1.13 MiB

    convert_w<<<dim3(Kd * Nd / 1024), dim3(256), 0, stream>>>(Wm, Wb);
    patch_embed_gemm<<<dim3(NBLK), dim3(512), 0, stream>>>(x, Wb, bs, outp);
}